// Round 1
// baseline (91.598 us; speedup 1.0000x reference)
//
#include <hip/hip_runtime.h>
#include <hip/hip_bf16.h>

#define KD     128
#define LOWD   64
#define STUN   50000
#define BATCH  4096
#define BBP    8     // batch elems per block in prep kernel
#define BB2    4     // batch elems per block in final kernel
#define LOG2E  1.4426950408889634f

__device__ __forceinline__ float fexp2(float x){ return __builtin_amdgcn_exp2f(x); }
__device__ __forceinline__ float frcp (float x){ return __builtin_amdgcn_rcpf(x); }
__device__ __forceinline__ float fsig (float x){ return frcp(1.0f + fexp2(-LOG2E * x)); }

// ---------------------------------------------------------------------------
// K1: A1[k][j] = -log2e * sum_t kle[k][t] * W1[j][128+t]   (and A2 from W2)
// grid 256 blocks (128 for A1, 128 for A2), 128 threads
// ---------------------------------------------------------------------------
__global__ __launch_bounds__(128) void k_precompA(
    const float* __restrict__ kle,
    const float* __restrict__ W1,
    const float* __restrict__ W2,
    float* __restrict__ A1,
    float* __restrict__ A2)
{
    __shared__ float sk[64];
    const int bid   = blockIdx.x;
    const int which = bid >> 7;
    const int k     = bid & 127;
    const int j     = threadIdx.x;
    if (j < 64) sk[j] = kle[k * 64 + j];
    __syncthreads();
    const float* W = which ? W2 : W1;
    float acc = 0.f;
    #pragma unroll
    for (int t = 0; t < 64; ++t) acc += sk[t] * W[j * 192 + 128 + t];
    float* A = which ? A2 : A1;
    A[k * 128 + j] = -LOG2E * acc;
}

// ---------------------------------------------------------------------------
// K2: per-batch prep. 8 batch elems per block, 256 threads.
// half = t>>7 : 0 -> student path, 1 -> exercise path ; idx = t&127
// Produces s1o/s2o = -log2e * (e @ W{1,2}a.T)
// ---------------------------------------------------------------------------
__global__ __launch_bounds__(256) void k_prep(
    const int*   __restrict__ stu_id,
    const int*   __restrict__ exer_id,
    const float* __restrict__ student_emb,   // (2*50000, 64) flat
    const float* __restrict__ prompt_stu,    // (50000, 64)
    const float* __restrict__ kle,           // (128, 64)
    const float* __restrict__ k_diff,        // (20000, 64)
    const float* __restrict__ s_exer,        // (2, 64)
    const float* __restrict__ W1,            // (128, 192)
    const float* __restrict__ W2,
    const float* __restrict__ fc1_W,         // (128, 192)
    const float* __restrict__ fc1_b,
    const float* __restrict__ fc2_W,
    const float* __restrict__ fc2_b,
    float* __restrict__ s1o,                 // (B, 128)
    float* __restrict__ s2o)
{
    __shared__ float sh_in [4][64][BBP];   // 0:stu_row 1:sig(kd) 2:p_stu 3:sig(p_exer)
    __shared__ float sh_old[2][128][BBP];
    __shared__ float sh_e  [2][128][BBP];

    const int t  = threadIdx.x;
    const int b0 = blockIdx.x * BBP;

    // ---- load/gather phase: 32 threads per local batch elem ----
    {
        const int g  = t >> 5;       // local b
        const int l  = t & 31;
        const int gb = b0 + g;
        const int sid = stu_id[gb];
        const int eid = exer_id[gb];
        const int er  = (eid >= 10000) ? 1 : 0;
        #pragma unroll
        for (int it = 0; it < 2; ++it) {
            const int u = l + 32 * it;
            sh_in[0][u][g] = student_emb[sid * 64 + u];
            sh_in[1][u][g] = fsig(k_diff[eid * 64 + u]);
            sh_in[2][u][g] = prompt_stu[(sid % STUN) * 64 + u];
            sh_in[3][u][g] = fsig(s_exer[er * 64 + u]);
        }
    }
    __syncthreads();

    const int half = t >> 7;
    const int idx  = t & 127;
    float acc[BBP];

    // ---- stage 1: old[k] = sig( dot(row, kle[k]) ) ----
    #pragma unroll
    for (int b = 0; b < BBP; ++b) acc[b] = 0.f;
    #pragma unroll 4
    for (int u = 0; u < 64; ++u) {
        const float w = kle[idx * 64 + u];
        const float* p = &sh_in[half][u][0];
        #pragma unroll
        for (int b = 0; b < BBP; ++b) acc[b] += w * p[b];
    }
    #pragma unroll
    for (int b = 0; b < BBP; ++b) sh_old[half][idx][b] = fsig(acc[b]);
    __syncthreads();

    // ---- stage 2: e[i] = sig( [p, old] @ fcW[i] + fcb[i] ) ----
    {
        const float* fcW = half ? fc2_W : fc1_W;
        const float* fcb = half ? fc2_b : fc1_b;
        #pragma unroll
        for (int b = 0; b < BBP; ++b) acc[b] = 0.f;
        #pragma unroll 4
        for (int u = 0; u < 64; ++u) {
            const float w = fcW[idx * 192 + u];
            const float* p = &sh_in[2 + half][u][0];
            #pragma unroll
            for (int b = 0; b < BBP; ++b) acc[b] += w * p[b];
        }
        #pragma unroll 4
        for (int u = 0; u < 128; ++u) {
            const float w = fcW[idx * 192 + 64 + u];
            const float* p = &sh_old[half][u][0];
            #pragma unroll
            for (int b = 0; b < BBP; ++b) acc[b] += w * p[b];
        }
        const float bias = fcb[idx];
        #pragma unroll
        for (int b = 0; b < BBP; ++b) sh_e[half][idx][b] = fsig(acc[b] + bias);
    }
    __syncthreads();

    // ---- stage 3: s[j] = -log2e * dot(e, Wa[j]) ----
    {
        const float* Wm = half ? W2 : W1;
        float* sout = half ? s2o : s1o;
        #pragma unroll
        for (int b = 0; b < BBP; ++b) acc[b] = 0.f;
        #pragma unroll 4
        for (int u = 0; u < 128; ++u) {
            const float w = Wm[idx * 192 + u];
            const float* p = &sh_e[half][u][0];
            #pragma unroll
            for (int b = 0; b < BBP; ++b) acc[b] += w * p[b];
        }
        #pragma unroll
        for (int b = 0; b < BBP; ++b) sout[(b0 + b) * 128 + idx] = -LOG2E * acc[b];
    }
}

// ---------------------------------------------------------------------------
// K3: out[b] = sum_k kn[b,k]*sig(b3 + sum_j (sig1-sig2)*W3[j]) / sum_k kn[b,k]
// 4 batch elems per block, 256 threads: t -> (k = t>>1, half64 = t&1)
// ---------------------------------------------------------------------------
__global__ __launch_bounds__(256) void k_final(
    const float* __restrict__ s1o,
    const float* __restrict__ s2o,
    const float* __restrict__ A1,
    const float* __restrict__ A2,
    const float* __restrict__ W3,
    const float* __restrict__ b3,
    const float* __restrict__ kn,
    float* __restrict__ out)
{
    __shared__ float sh_s[2][BB2][128];
    __shared__ float red_o[BB2][4];
    __shared__ float red_k[BB2][4];

    const int t  = threadIdx.x;
    const int b0 = blockIdx.x * BB2;

    // load s1/s2 rows for the 4 batch elems (coalesced)
    #pragma unroll
    for (int it = 0; it < (2 * BB2 * 128) / 256; ++it) {
        const int idx   = t + 256 * it;
        const int which = idx >> 9;
        const int rem   = idx & 511;
        const int b     = rem >> 7;
        const int j     = rem & 127;
        sh_s[which][b][j] = (which ? s2o : s1o)[(b0 + b) * 128 + j];
    }
    __syncthreads();

    const int k = t >> 1;
    const int h = t & 1;
    const float bb3 = b3[0];

    float accb[BB2] = {0.f, 0.f, 0.f, 0.f};
    const float* A1r = &A1[k * 128 + h * 64];
    const float* A2r = &A2[k * 128 + h * 64];
    const float* w3r = &W3[h * 64];

    #pragma unroll 4
    for (int jj = 0; jj < 64; ++jj) {
        const float a1 = A1r[jj];
        const float a2 = A2r[jj];
        const float w3 = w3r[jj];
        const int   j  = h * 64 + jj;
        #pragma unroll
        for (int b = 0; b < BB2; ++b) {
            const float r1 = frcp(1.f + fexp2(sh_s[0][b][j] + a1));
            const float r2 = frcp(1.f + fexp2(sh_s[1][b][j] + a2));
            accb[b] += (r1 - r2) * w3;
        }
    }

    // combine the two j-halves (adjacent lanes)
    #pragma unroll
    for (int b = 0; b < BB2; ++b) accb[b] += __shfl_xor(accb[b], 1);

    float co[BB2], ck[BB2];
    #pragma unroll
    for (int b = 0; b < BB2; ++b) {
        const float o   = fsig(accb[b] + bb3);
        const float knv = kn[(b0 + b) * 128 + k];
        co[b] = (h == 0) ? o * knv : 0.f;
        ck[b] = (h == 0) ? knv : 0.f;
    }

    // wave reduce over 64 lanes
    #pragma unroll
    for (int off = 1; off < 64; off <<= 1) {
        #pragma unroll
        for (int b = 0; b < BB2; ++b) {
            co[b] += __shfl_xor(co[b], off);
            ck[b] += __shfl_xor(ck[b], off);
        }
    }
    if ((t & 63) == 0) {
        const int wid = t >> 6;
        #pragma unroll
        for (int b = 0; b < BB2; ++b) {
            red_o[b][wid] = co[b];
            red_k[b][wid] = ck[b];
        }
    }
    __syncthreads();
    if (t < BB2) {
        const float so = red_o[t][0] + red_o[t][1] + red_o[t][2] + red_o[t][3];
        const float sk = red_k[t][0] + red_k[t][1] + red_k[t][2] + red_k[t][3];
        out[b0 + t] = so / sk;
    }
}

// ---------------------------------------------------------------------------
extern "C" void kernel_launch(void* const* d_in, const int* in_sizes, int n_in,
                              void* d_out, int out_size, void* d_ws, size_t ws_size,
                              hipStream_t stream)
{
    const int*   stu_id      = (const int*)  d_in[0];
    const int*   exer_id     = (const int*)  d_in[1];
    const float* kn_emb      = (const float*)d_in[2];
    const float* student_emb = (const float*)d_in[3];
    const float* prompt_stu  = (const float*)d_in[4];
    const float* kle         = (const float*)d_in[5];
    const float* k_diff      = (const float*)d_in[6];
    const float* s_exer      = (const float*)d_in[7];
    const float* W1          = (const float*)d_in[8];
    const float* W2          = (const float*)d_in[9];
    const float* W3          = (const float*)d_in[10];
    const float* b3          = (const float*)d_in[11];
    const float* fc1_W       = (const float*)d_in[12];
    const float* fc1_b       = (const float*)d_in[13];
    const float* fc2_W       = (const float*)d_in[14];
    const float* fc2_b       = (const float*)d_in[15];
    float* out = (float*)d_out;

    float* ws  = (float*)d_ws;
    float* A1  = ws;
    float* A2  = ws + 128 * 128;
    float* s1o = ws + 2 * 128 * 128;
    float* s2o = s1o + BATCH * 128;

    k_precompA<<<256, 128, 0, stream>>>(kle, W1, W2, A1, A2);
    k_prep<<<BATCH / BBP, 256, 0, stream>>>(stu_id, exer_id, student_emb, prompt_stu,
                                            kle, k_diff, s_exer, W1, W2,
                                            fc1_W, fc1_b, fc2_W, fc2_b, s1o, s2o);
    k_final<<<BATCH / BB2, 256, 0, stream>>>(s1o, s2o, A1, A2, W3, b3, kn_emb, out);
}

// Round 2
// 71.170 us; speedup vs baseline: 1.2870x; 1.2870x over previous
//
#include <hip/hip_runtime.h>
#include <hip/hip_bf16.h>

#define STUN   50000
#define BATCH  4096
#define BBP    8     // batch elems per block in prep kernel
#define BB2    16    // batch elems per block in final kernel
#define LOG2E  1.4426950408889634f

__device__ __forceinline__ float fexp2(float x){ return __builtin_amdgcn_exp2f(x); }
__device__ __forceinline__ float frcp (float x){ return __builtin_amdgcn_rcpf(x); }
__device__ __forceinline__ float fsig (float x){ return frcp(1.0f + fexp2(-LOG2E * x)); }

// ---------------------------------------------------------------------------
// K0: transposes + A-matrix precompute.  960 blocks x 128 threads.
//   kleT [64][128], fc1T/fc2T [192][128], W1aT/W2aT [128][128],
//   A1T/A2T [j=128][k=128] = -log2e * (kle @ W{1,2}[:,128:].T) transposed
// ---------------------------------------------------------------------------
__global__ __launch_bounds__(128) void k_pre(
    const float* __restrict__ kle,
    const float* __restrict__ W1,
    const float* __restrict__ W2,
    const float* __restrict__ fc1_W,
    const float* __restrict__ fc2_W,
    float* __restrict__ kleT,
    float* __restrict__ fc1T,
    float* __restrict__ fc2T,
    float* __restrict__ W1aT,
    float* __restrict__ W2aT,
    float* __restrict__ A1T,
    float* __restrict__ A2T)
{
    const int bid = blockIdx.x;
    const int t   = threadIdx.x;   // 0..127
    if (bid < 64) {
        const int u = bid;
        kleT[u * 128 + t] = kle[t * 64 + u];
    } else if (bid < 256) {
        const int u = bid - 64;
        fc1T[u * 128 + t] = fc1_W[t * 192 + u];
    } else if (bid < 448) {
        const int u = bid - 256;
        fc2T[u * 128 + t] = fc2_W[t * 192 + u];
    } else if (bid < 576) {
        const int u = bid - 448;
        W1aT[u * 128 + t] = W1[t * 192 + u];
    } else if (bid < 704) {
        const int u = bid - 576;
        W2aT[u * 128 + t] = W2[t * 192 + u];
    } else if (bid < 832) {
        const int j = bid - 704;
        float acc = 0.f;
        #pragma unroll 8
        for (int u = 0; u < 64; ++u)
            acc += kle[t * 64 + u] * W1[j * 192 + 128 + u];
        A1T[j * 128 + t] = -LOG2E * acc;
    } else {
        const int j = bid - 832;
        float acc = 0.f;
        #pragma unroll 8
        for (int u = 0; u < 64; ++u)
            acc += kle[t * 64 + u] * W2[j * 192 + 128 + u];
        A2T[j * 128 + t] = -LOG2E * acc;
    }
}

// ---------------------------------------------------------------------------
// K2: per-batch prep. 8 batch elems per block, 256 threads.
// half = t>>7 : 0 -> student path, 1 -> exercise path ; idx = t&127
// All weight reads coalesced via transposed layouts.
// Produces s1o/s2o = -log2e * (e @ W{1,2}a.T)
// ---------------------------------------------------------------------------
__global__ __launch_bounds__(256) void k_prep(
    const int*   __restrict__ stu_id,
    const int*   __restrict__ exer_id,
    const float* __restrict__ student_emb,   // (2*50000, 64) flat
    const float* __restrict__ prompt_stu,    // (50000, 64)
    const float* __restrict__ k_diff,        // (20000, 64)
    const float* __restrict__ s_exer,        // (2, 64)
    const float* __restrict__ kleT,          // (64, 128)
    const float* __restrict__ fc1T,          // (192, 128)
    const float* __restrict__ fc2T,
    const float* __restrict__ W1aT,          // (128, 128)
    const float* __restrict__ W2aT,
    const float* __restrict__ fc1_b,
    const float* __restrict__ fc2_b,
    float* __restrict__ s1o,                 // (B, 128)
    float* __restrict__ s2o)
{
    __shared__ float sh_in [4][64][BBP];   // 0:stu_row 1:sig(kd) 2:p_stu 3:sig(p_exer)
    __shared__ float sh_old[2][128][BBP];
    __shared__ float sh_e  [2][128][BBP];

    const int t  = threadIdx.x;
    const int b0 = blockIdx.x * BBP;

    // ---- load/gather phase: 32 threads per local batch elem ----
    {
        const int g  = t >> 5;       // local b
        const int l  = t & 31;
        const int gb = b0 + g;
        const int sid = stu_id[gb];
        const int eid = exer_id[gb];
        const int er  = (eid >= 10000) ? 1 : 0;
        #pragma unroll
        for (int it = 0; it < 2; ++it) {
            const int u = l + 32 * it;
            sh_in[0][u][g] = student_emb[sid * 64 + u];
            sh_in[1][u][g] = fsig(k_diff[eid * 64 + u]);
            sh_in[2][u][g] = prompt_stu[(sid % STUN) * 64 + u];
            sh_in[3][u][g] = fsig(s_exer[er * 64 + u]);
        }
    }
    __syncthreads();

    const int half = t >> 7;
    const int idx  = t & 127;
    float acc[BBP];

    // ---- stage 1: old[k] = sig( dot(row, kle[k]) ) ----
    #pragma unroll
    for (int b = 0; b < BBP; ++b) acc[b] = 0.f;
    #pragma unroll 4
    for (int u = 0; u < 64; ++u) {
        const float w  = kleT[u * 128 + idx];
        const float4 x0 = *(const float4*)&sh_in[half][u][0];
        const float4 x1 = *(const float4*)&sh_in[half][u][4];
        acc[0] += w * x0.x; acc[1] += w * x0.y; acc[2] += w * x0.z; acc[3] += w * x0.w;
        acc[4] += w * x1.x; acc[5] += w * x1.y; acc[6] += w * x1.z; acc[7] += w * x1.w;
    }
    #pragma unroll
    for (int b = 0; b < BBP; ++b) sh_old[half][idx][b] = fsig(acc[b]);
    __syncthreads();

    // ---- stage 2: e[i] = sig( [p, old] @ fcW[i] + fcb[i] ) ----
    {
        const float* fcT = half ? fc2T : fc1T;
        const float* fcb = half ? fc2_b : fc1_b;
        #pragma unroll
        for (int b = 0; b < BBP; ++b) acc[b] = 0.f;
        #pragma unroll 4
        for (int u = 0; u < 64; ++u) {
            const float w  = fcT[u * 128 + idx];
            const float4 x0 = *(const float4*)&sh_in[2 + half][u][0];
            const float4 x1 = *(const float4*)&sh_in[2 + half][u][4];
            acc[0] += w * x0.x; acc[1] += w * x0.y; acc[2] += w * x0.z; acc[3] += w * x0.w;
            acc[4] += w * x1.x; acc[5] += w * x1.y; acc[6] += w * x1.z; acc[7] += w * x1.w;
        }
        #pragma unroll 4
        for (int u = 0; u < 128; ++u) {
            const float w  = fcT[(64 + u) * 128 + idx];
            const float4 x0 = *(const float4*)&sh_old[half][u][0];
            const float4 x1 = *(const float4*)&sh_old[half][u][4];
            acc[0] += w * x0.x; acc[1] += w * x0.y; acc[2] += w * x0.z; acc[3] += w * x0.w;
            acc[4] += w * x1.x; acc[5] += w * x1.y; acc[6] += w * x1.z; acc[7] += w * x1.w;
        }
        const float bias = fcb[idx];
        #pragma unroll
        for (int b = 0; b < BBP; ++b) sh_e[half][idx][b] = fsig(acc[b] + bias);
    }
    __syncthreads();

    // ---- stage 3: s[j] = -log2e * dot(e, Wa[j]) ----
    {
        const float* WT = half ? W2aT : W1aT;
        float* sout = half ? s2o : s1o;
        #pragma unroll
        for (int b = 0; b < BBP; ++b) acc[b] = 0.f;
        #pragma unroll 4
        for (int u = 0; u < 128; ++u) {
            const float w  = WT[u * 128 + idx];
            const float4 x0 = *(const float4*)&sh_e[half][u][0];
            const float4 x1 = *(const float4*)&sh_e[half][u][4];
            acc[0] += w * x0.x; acc[1] += w * x0.y; acc[2] += w * x0.z; acc[3] += w * x0.w;
            acc[4] += w * x1.x; acc[5] += w * x1.y; acc[6] += w * x1.z; acc[7] += w * x1.w;
        }
        #pragma unroll
        for (int b = 0; b < BBP; ++b) sout[(b0 + b) * 128 + idx] = -LOG2E * acc[b];
    }
}

// ---------------------------------------------------------------------------
// K3: out[b] = sum_k kn[b,k]*sig(b3 + sum_j (sig1-sig2)*W3[j]) / sum_k kn[b,k]
// 16 batch elems per block, 1024 threads; wave w -> b0+w; lanes -> k, k+64.
// A matrices staged in LDS in 32-row j-tiles, coalesced.
// ---------------------------------------------------------------------------
__global__ __launch_bounds__(1024) void k_final(
    const float* __restrict__ s1o,
    const float* __restrict__ s2o,
    const float* __restrict__ A1T,   // (128 j, 128 k), pre-scaled
    const float* __restrict__ A2T,
    const float* __restrict__ W3,
    const float* __restrict__ b3,
    const float* __restrict__ kn,
    float* __restrict__ out)
{
    __shared__ float sA1[32][128];
    __shared__ float sA2[32][128];
    __shared__ float sh_s[2][BB2][128];
    __shared__ float sW3[128];

    const int t  = threadIdx.x;
    const int b0 = blockIdx.x * BB2;

    // load s1/s2 rows for the 16 batch elems (coalesced)
    #pragma unroll
    for (int i = 0; i < (2 * BB2 * 128) / 1024; ++i) {
        const int idx   = t + 1024 * i;
        const int which = idx >> 11;
        const int rem   = idx & 2047;
        const int b     = rem >> 7;
        const int j     = rem & 127;
        sh_s[which][b][j] = (which ? s2o : s1o)[(b0 + b) * 128 + j];
    }
    if (t < 128) sW3[t] = W3[t];
    __syncthreads();

    const int w   = t >> 6;       // wave id -> local batch elem
    const int kk  = t & 63;       // k and k+64
    const int b   = b0 + w;
    const float bb3 = b3[0];

    float acc0 = 0.f, acc1 = 0.f;

    for (int j0 = 0; j0 < 128; j0 += 32) {
        // stage 32x128 of A1T and A2T (coalesced float4)
        {
            const float4* gA1 = (const float4*)&A1T[j0 * 128];
            const float4* gA2 = (const float4*)&A2T[j0 * 128];
            float4* lA1 = (float4*)&sA1[0][0];
            float4* lA2 = (float4*)&sA2[0][0];
            lA1[t] = gA1[t];
            lA2[t] = gA2[t];
        }
        __syncthreads();

        #pragma unroll 4
        for (int jj = 0; jj < 32; ++jj) {
            const int j   = j0 + jj;
            const float s1v = sh_s[0][w][j];
            const float s2v = sh_s[1][w][j];
            const float w3  = sW3[j];
            const float a1lo = sA1[jj][kk];
            const float a1hi = sA1[jj][kk + 64];
            const float a2lo = sA2[jj][kk];
            const float a2hi = sA2[jj][kk + 64];
            const float r1lo = frcp(1.f + fexp2(s1v + a1lo));
            const float r2lo = frcp(1.f + fexp2(s2v + a2lo));
            const float r1hi = frcp(1.f + fexp2(s1v + a1hi));
            const float r2hi = frcp(1.f + fexp2(s2v + a2hi));
            acc0 += (r1lo - r2lo) * w3;
            acc1 += (r1hi - r2hi) * w3;
        }
        __syncthreads();
    }

    const float o0  = fsig(acc0 + bb3);
    const float o1  = fsig(acc1 + bb3);
    const float kn0 = kn[b * 128 + kk];
    const float kn1 = kn[b * 128 + kk + 64];
    float co = o0 * kn0 + o1 * kn1;
    float ck = kn0 + kn1;
    #pragma unroll
    for (int off = 1; off < 64; off <<= 1) {
        co += __shfl_xor(co, off);
        ck += __shfl_xor(ck, off);
    }
    if (kk == 0) out[b] = co / ck;
}

// ---------------------------------------------------------------------------
extern "C" void kernel_launch(void* const* d_in, const int* in_sizes, int n_in,
                              void* d_out, int out_size, void* d_ws, size_t ws_size,
                              hipStream_t stream)
{
    const int*   stu_id      = (const int*)  d_in[0];
    const int*   exer_id     = (const int*)  d_in[1];
    const float* kn_emb      = (const float*)d_in[2];
    const float* student_emb = (const float*)d_in[3];
    const float* prompt_stu  = (const float*)d_in[4];
    const float* kle         = (const float*)d_in[5];
    const float* k_diff      = (const float*)d_in[6];
    const float* s_exer      = (const float*)d_in[7];
    const float* W1          = (const float*)d_in[8];
    const float* W2          = (const float*)d_in[9];
    const float* W3          = (const float*)d_in[10];
    const float* b3          = (const float*)d_in[11];
    const float* fc1_W       = (const float*)d_in[12];
    const float* fc1_b       = (const float*)d_in[13];
    const float* fc2_W       = (const float*)d_in[14];
    const float* fc2_b       = (const float*)d_in[15];
    float* out = (float*)d_out;

    float* ws   = (float*)d_ws;
    float* kleT = ws;                        // 64*128    = 8192
    float* fc1T = kleT + 8192;               // 192*128   = 24576
    float* fc2T = fc1T + 24576;
    float* W1aT = fc2T + 24576;              // 128*128   = 16384
    float* W2aT = W1aT + 16384;
    float* A1T  = W2aT + 16384;
    float* A2T  = A1T  + 16384;
    float* s1o  = A2T  + 16384;              // 4096*128
    float* s2o  = s1o  + BATCH * 128;

    k_pre<<<960, 128, 0, stream>>>(kle, W1, W2, fc1_W, fc2_W,
                                   kleT, fc1T, fc2T, W1aT, W2aT, A1T, A2T);
    k_prep<<<BATCH / BBP, 256, 0, stream>>>(stu_id, exer_id, student_emb, prompt_stu,
                                            k_diff, s_exer, kleT, fc1T, fc2T,
                                            W1aT, W2aT, fc1_b, fc2_b, s1o, s2o);
    k_final<<<BATCH / BB2, 1024, 0, stream>>>(s1o, s2o, A1T, A2T, W3, b3, kn_emb, out);
}

// Round 3
// 64.992 us; speedup vs baseline: 1.4094x; 1.0951x over previous
//
#include <hip/hip_runtime.h>
#include <hip/hip_bf16.h>

#define STUN   50000
#define BATCH  4096
#define BBP    8     // batch elems per block in prep kernel
#define LOG2E  1.4426950408889634f

__device__ __forceinline__ float fexp2(float x){ return __builtin_amdgcn_exp2f(x); }
__device__ __forceinline__ float frcp (float x){ return __builtin_amdgcn_rcpf(x); }
__device__ __forceinline__ float fsig (float x){ return frcp(1.0f + fexp2(-LOG2E * x)); }
// pre-scaled domain: x already multiplied by -log2e
__device__ __forceinline__ float fsigp(float x){ return frcp(1.0f + fexp2(x)); }

// ---------------------------------------------------------------------------
// K0: weight repack (float4-interleaved) + A-matrix precompute.
// Layouts produced:
//   kle4 [u4=16][idx=128][4]  = kle[idx][u4*4+c]
//   fc1i/fc2i [u4=48][128][4] = fcW[idx][u4*4+c]
//   W1ai/W2ai [u4=32][128][4] = W[idx][u4*4+c]        (the 'a' half, u<128)
//   A1KJ/A2KJ [k=128][j=128]  = -log2e * sum_t kle[k][t]*W[j][128+t]
// grid 432 blocks x 128 threads
// ---------------------------------------------------------------------------
__global__ __launch_bounds__(128) void k_pre(
    const float* __restrict__ kle,
    const float* __restrict__ W1,
    const float* __restrict__ W2,
    const float* __restrict__ fc1_W,
    const float* __restrict__ fc2_W,
    float* __restrict__ kle4,
    float* __restrict__ fc1i,
    float* __restrict__ fc2i,
    float* __restrict__ W1ai,
    float* __restrict__ W2ai,
    float* __restrict__ A1KJ,
    float* __restrict__ A2KJ)
{
    const int bid = blockIdx.x;
    const int t   = threadIdx.x;   // 0..127
    if (bid < 16) {
        const int u4 = bid;
        float4 v;
        v.x = kle[t * 64 + u4 * 4 + 0];
        v.y = kle[t * 64 + u4 * 4 + 1];
        v.z = kle[t * 64 + u4 * 4 + 2];
        v.w = kle[t * 64 + u4 * 4 + 3];
        *(float4*)&kle4[(u4 * 128 + t) * 4] = v;
    } else if (bid < 64) {
        const int u4 = bid - 16;
        float4 v;
        v.x = fc1_W[t * 192 + u4 * 4 + 0];
        v.y = fc1_W[t * 192 + u4 * 4 + 1];
        v.z = fc1_W[t * 192 + u4 * 4 + 2];
        v.w = fc1_W[t * 192 + u4 * 4 + 3];
        *(float4*)&fc1i[(u4 * 128 + t) * 4] = v;
    } else if (bid < 112) {
        const int u4 = bid - 64;
        float4 v;
        v.x = fc2_W[t * 192 + u4 * 4 + 0];
        v.y = fc2_W[t * 192 + u4 * 4 + 1];
        v.z = fc2_W[t * 192 + u4 * 4 + 2];
        v.w = fc2_W[t * 192 + u4 * 4 + 3];
        *(float4*)&fc2i[(u4 * 128 + t) * 4] = v;
    } else if (bid < 144) {
        const int u4 = bid - 112;
        float4 v;
        v.x = W1[t * 192 + u4 * 4 + 0];
        v.y = W1[t * 192 + u4 * 4 + 1];
        v.z = W1[t * 192 + u4 * 4 + 2];
        v.w = W1[t * 192 + u4 * 4 + 3];
        *(float4*)&W1ai[(u4 * 128 + t) * 4] = v;
    } else if (bid < 176) {
        const int u4 = bid - 144;
        float4 v;
        v.x = W2[t * 192 + u4 * 4 + 0];
        v.y = W2[t * 192 + u4 * 4 + 1];
        v.z = W2[t * 192 + u4 * 4 + 2];
        v.w = W2[t * 192 + u4 * 4 + 3];
        *(float4*)&W2ai[(u4 * 128 + t) * 4] = v;
    } else if (bid < 304) {
        const int j = bid - 176;          // lane t = k
        float acc = 0.f;
        #pragma unroll 8
        for (int u = 0; u < 64; ++u)
            acc += kle[t * 64 + u] * W1[j * 192 + 128 + u];
        A1KJ[t * 128 + j] = -LOG2E * acc;
    } else {
        const int j = bid - 304;
        float acc = 0.f;
        #pragma unroll 8
        for (int u = 0; u < 64; ++u)
            acc += kle[t * 64 + u] * W2[j * 192 + 128 + u];
        A2KJ[t * 128 + j] = -LOG2E * acc;
    }
}

// ---------------------------------------------------------------------------
// K2: per-batch prep. 8 batch elems per block, 256 threads.
// half = t>>7 : 0 -> student path, 1 -> exercise path ; idx = t&127
// Weight loads: float4 (16 B/lane) coalesced from interleaved layouts.
// Produces s1o/s2o = -log2e * (e @ W{1,2}a.T)
// ---------------------------------------------------------------------------
__global__ __launch_bounds__(256) void k_prep(
    const int*   __restrict__ stu_id,
    const int*   __restrict__ exer_id,
    const float* __restrict__ student_emb,   // (2*50000, 64) flat
    const float* __restrict__ prompt_stu,    // (50000, 64)
    const float* __restrict__ k_diff,        // (20000, 64)
    const float* __restrict__ s_exer,        // (2, 64)
    const float* __restrict__ kle4,
    const float* __restrict__ fc1i,
    const float* __restrict__ fc2i,
    const float* __restrict__ W1ai,
    const float* __restrict__ W2ai,
    const float* __restrict__ fc1_b,
    const float* __restrict__ fc2_b,
    float* __restrict__ s1o,                 // (B, 128)
    float* __restrict__ s2o)
{
    __shared__ float sh_in [4][64][BBP];   // 0:stu_row 1:sig(kd) 2:p_stu 3:sig(p_exer)
    __shared__ float sh_old[2][128][BBP];
    __shared__ float sh_e  [2][128][BBP];

    const int t  = threadIdx.x;
    const int b0 = blockIdx.x * BBP;

    // ---- load/gather phase: 32 threads per local batch elem ----
    {
        const int g  = t >> 5;       // local b
        const int l  = t & 31;
        const int gb = b0 + g;
        const int sid = stu_id[gb];
        const int eid = exer_id[gb];
        const int er  = (eid >= 10000) ? 1 : 0;
        #pragma unroll
        for (int it = 0; it < 2; ++it) {
            const int u = l + 32 * it;
            sh_in[0][u][g] = student_emb[sid * 64 + u];
            sh_in[1][u][g] = fsig(k_diff[eid * 64 + u]);
            sh_in[2][u][g] = prompt_stu[(sid % STUN) * 64 + u];
            sh_in[3][u][g] = fsig(s_exer[er * 64 + u]);
        }
    }
    __syncthreads();

    const int half = t >> 7;
    const int idx  = t & 127;
    float acc[BBP];

#define FMA8(xbase) { \
        const float4 x0 = *(const float4*)&(xbase)[0]; \
        const float4 x1 = *(const float4*)&(xbase)[4]; \
        acc[0] += wv * x0.x; acc[1] += wv * x0.y; acc[2] += wv * x0.z; acc[3] += wv * x0.w; \
        acc[4] += wv * x1.x; acc[5] += wv * x1.y; acc[6] += wv * x1.z; acc[7] += wv * x1.w; }

    // ---- stage 1: old[k] = sig( dot(row, kle[k]) ) ----
    #pragma unroll
    for (int b = 0; b < BBP; ++b) acc[b] = 0.f;
    #pragma unroll 4
    for (int u4 = 0; u4 < 16; ++u4) {
        const float4 w4 = *(const float4*)&kle4[(u4 * 128 + idx) * 4];
        { const float wv = w4.x; FMA8(sh_in[half][u4*4+0]); }
        { const float wv = w4.y; FMA8(sh_in[half][u4*4+1]); }
        { const float wv = w4.z; FMA8(sh_in[half][u4*4+2]); }
        { const float wv = w4.w; FMA8(sh_in[half][u4*4+3]); }
    }
    #pragma unroll
    for (int b = 0; b < BBP; ++b) sh_old[half][idx][b] = fsig(acc[b]);
    __syncthreads();

    // ---- stage 2: e[i] = sig( [p, old] @ fcW[i] + fcb[i] ) ----
    {
        const float* fcT = half ? fc2i : fc1i;
        const float* fcb = half ? fc2_b : fc1_b;
        #pragma unroll
        for (int b = 0; b < BBP; ++b) acc[b] = 0.f;
        #pragma unroll 4
        for (int u4 = 0; u4 < 16; ++u4) {
            const float4 w4 = *(const float4*)&fcT[(u4 * 128 + idx) * 4];
            { const float wv = w4.x; FMA8(sh_in[2+half][u4*4+0]); }
            { const float wv = w4.y; FMA8(sh_in[2+half][u4*4+1]); }
            { const float wv = w4.z; FMA8(sh_in[2+half][u4*4+2]); }
            { const float wv = w4.w; FMA8(sh_in[2+half][u4*4+3]); }
        }
        #pragma unroll 4
        for (int u4 = 16; u4 < 48; ++u4) {
            const float4 w4 = *(const float4*)&fcT[(u4 * 128 + idx) * 4];
            const int uo = (u4 - 16) * 4;
            { const float wv = w4.x; FMA8(sh_old[half][uo+0]); }
            { const float wv = w4.y; FMA8(sh_old[half][uo+1]); }
            { const float wv = w4.z; FMA8(sh_old[half][uo+2]); }
            { const float wv = w4.w; FMA8(sh_old[half][uo+3]); }
        }
        const float bias = fcb[idx];
        #pragma unroll
        for (int b = 0; b < BBP; ++b) sh_e[half][idx][b] = fsig(acc[b] + bias);
    }
    __syncthreads();

    // ---- stage 3: s[j] = -log2e * dot(e, Wa[j]) ----
    {
        const float* WT = half ? W2ai : W1ai;
        float* sout = half ? s2o : s1o;
        #pragma unroll
        for (int b = 0; b < BBP; ++b) acc[b] = 0.f;
        #pragma unroll 4
        for (int u4 = 0; u4 < 32; ++u4) {
            const float4 w4 = *(const float4*)&WT[(u4 * 128 + idx) * 4];
            { const float wv = w4.x; FMA8(sh_e[half][u4*4+0]); }
            { const float wv = w4.y; FMA8(sh_e[half][u4*4+1]); }
            { const float wv = w4.z; FMA8(sh_e[half][u4*4+2]); }
            { const float wv = w4.w; FMA8(sh_e[half][u4*4+3]); }
        }
        #pragma unroll
        for (int b = 0; b < BBP; ++b) sout[(b0 + b) * 128 + idx] = -LOG2E * acc[b];
    }
#undef FMA8
}

// ---------------------------------------------------------------------------
// K3: out[b] = sum_k kn[b,k]*sig(b3 + sum_j (sig1-sig2)*W3[j]) / sum_k kn[b,k]
// 512 threads = 8 waves; wave w -> batch elem b0+w; lane kk -> k in {kk,kk+64}
// A staged in LDS as [k][64-j tile] with XOR-unit swizzle -> conflict-free b128.
// grid 512 -> 2 blocks/CU, barriers never idle the whole CU.
// ---------------------------------------------------------------------------
__global__ __launch_bounds__(512, 4) void k_final(
    const float* __restrict__ s1o,
    const float* __restrict__ s2o,
    const float* __restrict__ A1KJ,   // (128 k, 128 j), pre-scaled by -log2e
    const float* __restrict__ A2KJ,
    const float* __restrict__ W3,
    const float* __restrict__ b3,
    const float* __restrict__ kn,
    float* __restrict__ out)
{
    __shared__ float sA1[128 * 64];       // [k][16 units][4], unit-swizzled
    __shared__ float sA2[128 * 64];
    __shared__ float sh_s[2][8][128];
    __shared__ float sW3[128];

    const int t  = threadIdx.x;           // 0..511
    const int b0 = blockIdx.x * 8;

    // load s1/s2 rows for the 8 batch elems (one float4 per thread)
    {
        const int which = t >> 8;
        const int rem   = t & 255;        // rem*4 in [0,1024)
        const int b     = rem >> 5;
        const int j     = (rem & 31) * 4;
        *(float4*)&sh_s[which][b][j] =
            *(const float4*)&((which ? s2o : s1o)[(b0 + b) * 128 + j]);
    }
    if (t < 32) *(float4*)&sW3[t * 4] = *(const float4*)&W3[t * 4];

    const int w  = t >> 6;                // wave id -> local batch elem
    const int kk = t & 63;
    const float bb3 = b3[0];

    float acc0 = 0.f, acc1 = 0.f;

    for (int p = 0; p < 2; ++p) {
        __syncthreads();                  // protect sA from previous phase readers
        // stage 64 j-columns of A1KJ and A2KJ, swizzled units
        #pragma unroll
        for (int i = 0; i < 4; ++i) {
            const int gu = i * 512 + t;   // unit id 0..2047
            const int k  = gu >> 4;
            const int f4 = gu & 15;
            const int su = f4 ^ (k & 15);
            ((float4*)sA1)[k * 16 + su] = *(const float4*)&A1KJ[k * 128 + p * 64 + f4 * 4];
            ((float4*)sA2)[k * 16 + su] = *(const float4*)&A2KJ[k * 128 + p * 64 + f4 * 4];
        }
        __syncthreads();

        #pragma unroll 4
        for (int j4 = 0; j4 < 16; ++j4) {
            const int j = p * 64 + j4 * 4;
            const float4 s1 = *(const float4*)&sh_s[0][w][j];
            const float4 s2 = *(const float4*)&sh_s[1][w][j];
            const float4 w3 = *(const float4*)&sW3[j];
            const int su    = j4 ^ (kk & 15);
            const float4 a1lo = ((const float4*)sA1)[ kk       * 16 + su];
            const float4 a1hi = ((const float4*)sA1)[(kk + 64) * 16 + su];
            const float4 a2lo = ((const float4*)sA2)[ kk       * 16 + su];
            const float4 a2hi = ((const float4*)sA2)[(kk + 64) * 16 + su];

            acc0 += (fsigp(s1.x + a1lo.x) - fsigp(s2.x + a2lo.x)) * w3.x;
            acc0 += (fsigp(s1.y + a1lo.y) - fsigp(s2.y + a2lo.y)) * w3.y;
            acc0 += (fsigp(s1.z + a1lo.z) - fsigp(s2.z + a2lo.z)) * w3.z;
            acc0 += (fsigp(s1.w + a1lo.w) - fsigp(s2.w + a2lo.w)) * w3.w;
            acc1 += (fsigp(s1.x + a1hi.x) - fsigp(s2.x + a2hi.x)) * w3.x;
            acc1 += (fsigp(s1.y + a1hi.y) - fsigp(s2.y + a2hi.y)) * w3.y;
            acc1 += (fsigp(s1.z + a1hi.z) - fsigp(s2.z + a2hi.z)) * w3.z;
            acc1 += (fsigp(s1.w + a1hi.w) - fsigp(s2.w + a2hi.w)) * w3.w;
        }
    }

    const int b = b0 + w;
    const float o0  = fsig(acc0 + bb3);
    const float o1  = fsig(acc1 + bb3);
    const float kn0 = kn[b * 128 + kk];
    const float kn1 = kn[b * 128 + kk + 64];
    float co = o0 * kn0 + o1 * kn1;
    float ck = kn0 + kn1;
    #pragma unroll
    for (int off = 1; off < 64; off <<= 1) {
        co += __shfl_xor(co, off);
        ck += __shfl_xor(ck, off);
    }
    if (kk == 0) out[b] = co / ck;
}

// ---------------------------------------------------------------------------
extern "C" void kernel_launch(void* const* d_in, const int* in_sizes, int n_in,
                              void* d_out, int out_size, void* d_ws, size_t ws_size,
                              hipStream_t stream)
{
    const int*   stu_id      = (const int*)  d_in[0];
    const int*   exer_id     = (const int*)  d_in[1];
    const float* kn_emb      = (const float*)d_in[2];
    const float* student_emb = (const float*)d_in[3];
    const float* prompt_stu  = (const float*)d_in[4];
    const float* kle         = (const float*)d_in[5];
    const float* k_diff      = (const float*)d_in[6];
    const float* s_exer      = (const float*)d_in[7];
    const float* W1          = (const float*)d_in[8];
    const float* W2          = (const float*)d_in[9];
    const float* W3          = (const float*)d_in[10];
    const float* b3          = (const float*)d_in[11];
    const float* fc1_W       = (const float*)d_in[12];
    const float* fc1_b       = (const float*)d_in[13];
    const float* fc2_W       = (const float*)d_in[14];
    const float* fc2_b       = (const float*)d_in[15];
    float* out = (float*)d_out;

    float* ws   = (float*)d_ws;
    float* kle4 = ws;                        // 16*128*4  = 8192
    float* fc1i = kle4 + 8192;               // 48*128*4  = 24576
    float* fc2i = fc1i + 24576;
    float* W1ai = fc2i + 24576;              // 32*128*4  = 16384
    float* W2ai = W1ai + 16384;
    float* A1KJ = W2ai + 16384;              // 128*128
    float* A2KJ = A1KJ + 16384;
    float* s1o  = A2KJ + 16384;              // 4096*128
    float* s2o  = s1o  + BATCH * 128;

    k_pre<<<432, 128, 0, stream>>>(kle, W1, W2, fc1_W, fc2_W,
                                   kle4, fc1i, fc2i, W1ai, W2ai, A1KJ, A2KJ);
    k_prep<<<BATCH / BBP, 256, 0, stream>>>(stu_id, exer_id, student_emb, prompt_stu,
                                            k_diff, s_exer, kle4, fc1i, fc2i,
                                            W1ai, W2ai, fc1_b, fc2_b, s1o, s2o);
    k_final<<<BATCH / 8, 512, 0, stream>>>(s1o, s2o, A1KJ, A2KJ, W3, b3, kn_emb, out);
}